// Round 8
// baseline (428.348 us; speedup 1.0000x reference)
//
#include <hip/hip_runtime.h>
#include <math.h>

// ---------------------------------------------------------------------------
// FFT_MLP_KAN v6: FFT -> transpose -> 4 KAN layers (transposed activations,
// chunk-padded weights, double-buffered single-barrier LDS pipeline) ->
// 3 folded heads. All fp32.
// ---------------------------------------------------------------------------

__device__ __forceinline__ float silu_f(float x) {
    return x / (1.f + __expf(-x));
}

// ---------------------------------------------------------------------------
// FFT features -> F0 [P][27] (27 = abs_prev9, angle_cur9, abs_cur9; the
// reference's 4th block duplicates block 2 -> folded into L1 weights).
// ---------------------------------------------------------------------------
__global__ __launch_bounds__(128) void fft_kernel(const float* __restrict__ x,
                                                  float* __restrict__ F0, int P) {
    __shared__ float xs[128 * 65];
    __shared__ float twc[288], tws[288];    // cos / sin(-2*pi*k*n/32)
    int tid = threadIdx.x;
    for (int t = tid; t < 288; t += 128) {
        int k = t >> 5, n = t & 31;
        int m = (k * n) & 31;
        float ang = -0.19634954084936207f * (float)m;
        float s, c;
        sincosf(ang, &s, &c);
        twc[t] = c; tws[t] = s;
    }
    int p0 = blockIdx.x * 128;
    for (int idx = tid; idx < 128 * 64; idx += 128) {
        int g = p0 * 64 + idx;
        float v = (g < P * 64) ? x[g] : 0.f;
        xs[(idx >> 6) * 65 + (idx & 63)] = v;
    }
    __syncthreads();
    int p = p0 + tid;
    if (p >= P) return;
    const float* row = &xs[tid * 65];
    float r[64];
#pragma unroll
    for (int n = 0; n < 64; ++n) r[n] = row[n];
    float outv[27];
#pragma unroll
    for (int k = 0; k < 9; ++k) {
        float rp = 0.f, ip = 0.f, rc = 0.f, ic = 0.f;
#pragma unroll
        for (int n = 0; n < 32; ++n) {
            float c = twc[k * 32 + n], s = tws[k * 32 + n];
            rp = fmaf(r[n], c, rp);
            ip = fmaf(r[n], s, ip);
            rc = fmaf(r[n + 32], c, rc);
            ic = fmaf(r[n + 32], s, ic);
        }
        float ap = sqrtf(fmaf(rp, rp, ip * ip));
        float ac = sqrtf(fmaf(rc, rc, ic * ic));
        float gc = atan2f(ic, rc);
        outv[k] = ap; outv[9 + k] = gc; outv[18 + k] = ac;
    }
    float* dst = &F0[(size_t)p * 27];
#pragma unroll
    for (int q = 0; q < 27; ++q) dst[q] = outv[q];
}

// ---------------------------------------------------------------------------
// Transpose F0 [B*14][27] -> F0T [378][B].
// ---------------------------------------------------------------------------
__global__ __launch_bounds__(256) void transpose_f0_kernel(const float* __restrict__ F0,
                                                           float* __restrict__ F0T, int B) {
    __shared__ float t[448 * 27];
    int b0 = blockIdx.x * 32;
    const float* src = F0 + (size_t)b0 * 14 * 27;
    for (int idx = threadIdx.x; idx < 448 * 27; idx += 256) t[idx] = src[idx];
    __syncthreads();
    for (int idx = threadIdx.x; idx < 378 * 32; idx += 256) {
        int i = idx >> 5, bb = idx & 31;
        int ch = i / 27, q = i - ch * 27;
        F0T[(size_t)i * B + b0 + bb] = t[(bb * 14 + ch) * 27 + q];
    }
}

// ---------------------------------------------------------------------------
// Prep: chunk-padded fused weights.
//   Wfp[((jg*NHALF + half) * 28*CT*12) + (kc*CT + ct)*12 + r]
// jg = i/2 (chunk of 2 inputs), kc = (i&1)*14 + c, o = half*OUT_T + ct*10 + r.
// c=0 -> base_w, c>=1 -> spline_w*scaler. r in [10,12) pads to 0.
// ---------------------------------------------------------------------------
__device__ __forceinline__ float kval(const float* __restrict__ bw,
                                      const float* __restrict__ sw,
                                      const float* __restrict__ sc,
                                      int IN, int o, int s, int c) {
    if (c == 0) return bw[o * IN + s];
    return sw[((size_t)o * IN + s) * 13 + (c - 1)] * sc[o * IN + s];
}

__global__ void prep_all_kernel(float* __restrict__ Wfp1, float* __restrict__ Wfp2,
                                float* __restrict__ Wfp3, float* __restrict__ Wfp4,
                                float* __restrict__ W21, float* __restrict__ b21,
                                const float* k1b, const float* k1s, const float* k1c,
                                const float* k2b, const float* k2s, const float* k2c,
                                const float* k3b, const float* k3s, const float* k3c,
                                const float* k4b, const float* k4s, const float* k4c,
                                const float* W1, const float* b1,
                                const float* W2, const float* b2) {
    const int T1 = 189 * 2688, T2 = 40 * 2 * 2688, T3 = 80 * 2688, T4 = 40 * 1344;
    int id = blockIdx.x * 256 + threadIdx.x;
    if (id < T1) {                            // L1: 378 in (27-fold), 80 out
        int jg = id / 2688, t = id % 2688;
        int kc = t / 96, t2 = t % 96, ct = t2 / 12, r = t2 % 12;
        int i = 2 * jg + kc / 14, c = kc % 14, o = ct * 10 + r;
        float v = 0.f;
        if (r < 10) {
            int ch = i / 27, q = i - ch * 27, s1 = ch * 36 + q;
            v = kval(k1b, k1s, k1c, 504, o, s1, c);
            if (q >= 9 && q < 18) v += kval(k1b, k1s, k1c, 504, o, s1 + 18, c);
        }
        Wfp1[id] = v; return;
    }
    id -= T1;
    if (id < T2) {                            // L2: 80 in, 160 out (2 halves)
        int jg = id / (2 * 2688), rem = id % (2 * 2688), half = rem / 2688, t = rem % 2688;
        int kc = t / 96, t2 = t % 96, ct = t2 / 12, r = t2 % 12;
        int i = 2 * jg + kc / 14, c = kc % 14, o = half * 80 + ct * 10 + r;
        Wfp2[id] = (r < 10) ? kval(k2b, k2s, k2c, 80, o, i, c) : 0.f; return;
    }
    id -= T2;
    if (id < T3) {                            // L3: 160 in, 80 out
        int jg = id / 2688, t = id % 2688;
        int kc = t / 96, t2 = t % 96, ct = t2 / 12, r = t2 % 12;
        int i = 2 * jg + kc / 14, c = kc % 14, o = ct * 10 + r;
        Wfp3[id] = (r < 10) ? kval(k3b, k3s, k3c, 160, o, i, c) : 0.f; return;
    }
    id -= T3;
    if (id < T4) {                            // L4: 80 in, 40 out
        int jg = id / 1344, t = id % 1344;
        int kc = t / 48, t2 = t % 48, ct = t2 / 12, r = t2 % 12;
        int i = 2 * jg + kc / 14, c = kc % 14, o = ct * 10 + r;
        Wfp4[id] = (r < 10) ? kval(k4b, k4s, k4c, 80, o, i, c) : 0.f; return;
    }
    id -= T4;
    if (id < 3 * 20 * 40) {                   // heads fold: W21 = W2 @ W1
        int k = id % 40, rem = id / 40, j = rem % 20, h = rem / 20;
        float a = 0.f;
        for (int m = 0; m < 40; ++m)
            a = fmaf(W2[(h * 20 + j) * 40 + m], W1[(h * 40 + m) * 40 + k], a);
        W21[id] = a;
    } else if (id < 3 * 20 * 40 + 60) {
        int t = id - 2400, j = t % 20, h = t / 20;
        float a = b2[h * 20 + j];
        for (int m = 0; m < 40; ++m)
            a = fmaf(W2[(h * 20 + j) * 40 + m], b1[h * 40 + m], a);
        b21[t] = a;
    }
}

// ---------------------------------------------------------------------------
// KAN layer v6: double-buffered LDS, ONE barrier per chunk.
// Body j: commit buf[(j+1)&1] (regs->LDS, loaded a full chunk earlier) ->
//         issue chunk j+2 global loads -> FMA over buf[j&1] -> barrier.
// Loads get the whole FMA phase before the barrier's vmcnt drain.
// ---------------------------------------------------------------------------
template <int OUT_T, int KC, int NHALF>
__global__ __launch_bounds__(256) void kan6_kernel(const float* __restrict__ XT, int B,
                                                   const float* __restrict__ Wfp,
                                                   float* __restrict__ YpT, int OUTF) {
    constexpr int BM = 128;
    constexpr int NR = 10;
    constexpr int COLS_T = OUT_T / NR;       // 8 or 4
    constexpr int ROWS_T = 256 / COLS_T;     // 32 or 64
    constexpr int MR = BM / ROWS_T;          // 4 or 2
    constexpr int NW = 28 * COLS_T * 12;
    constexpr int NCH = KC / 2;
    constexpr int WSTG = (NW + 255) / 256;
    static_assert(COLS_T * NR == OUT_T, "cols");
    static_assert(ROWS_T * MR == BM, "rows");
    static_assert(KC % 2 == 0, "even KC");

    __shared__ float Ws[2][NW];
    __shared__ float Ft[2][28 * BM];

    const int tid = threadIdx.x;
    const int rt = tid % ROWS_T, ct = tid / ROWS_T;
    const int b0 = blockIdx.x * BM;
    const int s = blockIdx.y;
    const int half = blockIdx.z;
    const int ibase = s * KC;
    const int kk = tid >> 7;
    const int rr = tid & 127;

    const size_t wstride = (size_t)NHALF * NW;
    const size_t wbase0 = ((size_t)(ibase / 2) * NHALF + half) * NW;

    float acc[MR][NR];
#pragma unroll
    for (int m = 0; m < MR; ++m)
#pragma unroll
        for (int n = 0; n < NR; ++n) acc[m][n] = 0.f;

    float wreg[WSTG];
    float xreg;

    auto loadw = [&](int jc) {
        const float* src = Wfp + wbase0 + (size_t)jc * wstride;
#pragma unroll
        for (int u = 0; u < WSTG; ++u) {
            int t = tid + u * 256;
            if (t < NW) wreg[u] = src[t];
        }
        xreg = XT[(size_t)(ibase + 2 * jc + kk) * B + b0 + rr];
    };
    auto commit = [&](int pb) {
#pragma unroll
        for (int u = 0; u < WSTG; ++u) {
            int t = tid + u * 256;
            if (t < NW) Ws[pb][t] = wreg[u];
        }
        float xs = xreg;
        float* dst = &Ft[pb][kk * 14 * BM + rr];
        dst[0] = silu_f(xs);
#pragma unroll
        for (int c = 1; c < 14; ++c) dst[c * BM] = 0.f;
        float t10 = (xs + 0.3f) * 10.f;
        if (t10 >= 0.f && t10 < 16.f) {
            int jj = (int)t10;
            float u = t10 - (float)jj;
            float u2 = u * u, u3 = u2 * u, v = 1.f - u;
            float B0 = v * v * v * (1.f / 6.f);
            float B1 = (3.f * u3 - 6.f * u2 + 4.f) * (1.f / 6.f);
            float B2 = (-3.f * u3 + 3.f * u2 + 3.f * u + 1.f) * (1.f / 6.f);
            float B3 = u3 * (1.f / 6.f);
            int bs = jj - 3;
#pragma unroll
            for (int t = 0; t < 4; ++t) {
                int rw = bs + t;
                float bb = (t == 0) ? B0 : (t == 1) ? B1 : (t == 2) ? B2 : B3;
                if (rw >= 0 && rw <= 12) dst[(1 + rw) * BM] = bb;
            }
        }
    };

    // prologue: chunk 0 -> buf0; issue chunk 1 loads
    loadw(0);
    commit(0);
    if (NCH > 1) loadw(1);
    __syncthreads();

    for (int j = 0; j < NCH; ++j) {
        if (j + 1 < NCH) {
            commit((j + 1) & 1);
            if (j + 2 < NCH) loadw(j + 2);
        }
        const int pb = j & 1;
#pragma unroll
        for (int kc = 0; kc < 28; ++kc) {
            const float* wb = &Ws[pb][(kc * COLS_T + ct) * 12];
            float4 w0 = *(const float4*)(wb);
            float4 w1 = *(const float4*)(wb + 4);
            float2 w2 = *(const float2*)(wb + 8);
            float wn[NR] = {w0.x, w0.y, w0.z, w0.w, w1.x, w1.y, w1.z, w1.w, w2.x, w2.y};
            const float* fb = &Ft[pb][kc * BM + rt * MR];
            float xm[MR];
            if constexpr (MR == 4) {
                float4 f = *(const float4*)fb;
                xm[0] = f.x; xm[1] = f.y; xm[2] = f.z; xm[3] = f.w;
            } else {
                float2 f = *(const float2*)fb;
                xm[0] = f.x; xm[1] = f.y;
            }
#pragma unroll
            for (int m = 0; m < MR; ++m)
#pragma unroll
                for (int n = 0; n < NR; ++n) acc[m][n] = fmaf(xm[m], wn[n], acc[m][n]);
        }
        if (j + 1 < NCH) __syncthreads();
    }

    // store partial: vectorized along b
    float* yd = YpT + (size_t)s * OUTF * B + (size_t)(half * OUT_T) * B;
#pragma unroll
    for (int n = 0; n < NR; ++n) {
        float* p = yd + (size_t)(ct * NR + n) * B + b0 + rt * MR;
        if constexpr (MR == 4)
            *(float4*)p = make_float4(acc[0][n], acc[1][n], acc[2][n], acc[3][n]);
        else
            *(float2*)p = make_float2(acc[0][n], acc[1][n]);
    }
}

__global__ void reduce_kernel(float* __restrict__ Y, const float* __restrict__ Yp,
                              int N, int KS) {
    int t = blockIdx.x * 256 + threadIdx.x;   // float4 index
    if (t * 4 >= N) return;
    float4 a = make_float4(0.f, 0.f, 0.f, 0.f);
    for (int s = 0; s < KS; ++s) {
        float4 v = *(const float4*)&Yp[(size_t)s * N + t * 4];
        a.x += v.x; a.y += v.y; a.z += v.z; a.w += v.w;
    }
    *(float4*)&Y[t * 4] = a;
}

// ---------------------------------------------------------------------------
// Heads: one thread per (b, head); h4T is [40][B].
// ---------------------------------------------------------------------------
__global__ __launch_bounds__(256) void heads_kernel(const float* __restrict__ h4T,
                                                    const float* __restrict__ W21,
                                                    const float* __restrict__ b21,
                                                    const float* __restrict__ W3,
                                                    const float* __restrict__ b3,
                                                    float* __restrict__ out, int B) {
    __shared__ float w21s[2400], b21s[60], w3s[60], b3s[3];
    int tid = threadIdx.x;
    for (int t = tid; t < 2400; t += 256) w21s[t] = W21[t];
    if (tid < 60) { b21s[tid] = b21[tid]; w3s[tid] = W3[tid]; }
    if (tid < 3) b3s[tid] = b3[tid];
    __syncthreads();
    int id = blockIdx.x * 256 + tid;
    if (id >= B * 3) return;
    int b = id / 3, h = id % 3;
    float hv[40];
#pragma unroll
    for (int m = 0; m < 40; ++m) hv[m] = h4T[(size_t)m * B + b];
    float z = b3s[h];
#pragma unroll
    for (int j = 0; j < 20; ++j) {
        float y = b21s[h * 20 + j];
        const float* wr = &w21s[(h * 20 + j) * 40];
#pragma unroll
        for (int m = 0; m < 40; ++m) y = fmaf(wr[m], hv[m], y);
        y = (y >= 0.f) ? y : 0.05f * y;
        z = fmaf(w3s[h * 20 + j], y, z);
    }
    out[id] = 1.f / (1.f + __expf(-z));
}

// ---------------------------------------------------------------------------
extern "C" void kernel_launch(void* const* d_in, const int* in_sizes, int n_in,
                              void* d_out, int out_size, void* d_ws, size_t ws_size,
                              hipStream_t stream) {
    const float* x   = (const float*)d_in[0];
    const float* k1b = (const float*)d_in[1];
    const float* k1s = (const float*)d_in[2];
    const float* k1c = (const float*)d_in[3];
    const float* k2b = (const float*)d_in[4];
    const float* k2s = (const float*)d_in[5];
    const float* k2c = (const float*)d_in[6];
    const float* k3b = (const float*)d_in[7];
    const float* k3s = (const float*)d_in[8];
    const float* k3c = (const float*)d_in[9];
    const float* k4b = (const float*)d_in[10];
    const float* k4s = (const float*)d_in[11];
    const float* k4c = (const float*)d_in[12];
    const float* hW1 = (const float*)d_in[13];
    const float* hb1 = (const float*)d_in[14];
    const float* hW2 = (const float*)d_in[15];
    const float* hb2 = (const float*)d_in[16];
    const float* hW3 = (const float*)d_in[17];
    const float* hb3 = (const float*)d_in[18];
    float* out = (float*)d_out;

    int B = in_sizes[0] / (64 * 14);
    int P = B * 14;

    float* ws = (float*)d_ws;
    size_t off = 0;
    float* Wfp1 = ws + off; off += 189 * 2688;
    float* Wfp2 = ws + off; off += 40 * 2 * 2688;
    float* Wfp3 = ws + off; off += 80 * 2688;
    float* Wfp4 = ws + off; off += 40 * 1344;
    float* W21  = ws + off; off += 2400;
    float* b21  = ws + off; off += 60;
    float* F0T  = ws + off; off += (size_t)B * 378;
    float* h1T  = ws + off; off += (size_t)B * 80;
    float* h2T  = ws + off; off += (size_t)B * 160;
    float* h3T  = ws + off; off += (size_t)B * 80;
    float* h4T  = ws + off; off += (size_t)B * 40;
    float* F0   = ws + off;                  // aliases Yp (dead after transpose)
    float* Yp   = ws + off;
    size_t cap = (ws_size / 4 > off) ? (ws_size / 4 - off) : 0;

    // tier select (ws_size constant per session -> same path every call)
    bool tierA = cap >= (size_t)800 * B;     // max partial need: S2=5 x 160

    // ---- prep ----
    {
        int total = 189 * 2688 + 40 * 2 * 2688 + 80 * 2688 + 40 * 1344 + 2460;
        prep_all_kernel<<<(total + 255) / 256, 256, 0, stream>>>(
            Wfp1, Wfp2, Wfp3, Wfp4, W21, b21,
            k1b, k1s, k1c, k2b, k2s, k2c, k3b, k3s, k3c, k4b, k4s, k4c,
            hW1, hb1, hW2, hb2);
    }

    // ---- FFT -> transpose ----
    fft_kernel<<<(P + 127) / 128, 128, 0, stream>>>(x, F0, P);
    transpose_f0_kernel<<<B / 32, 256, 0, stream>>>(F0, F0T, B);

    if (tierA) {
        // L1: 378->80, S=9 (KC=42, 21 chunks)
        kan6_kernel<80, 42, 1><<<dim3(B / 128, 9, 1), 256, 0, stream>>>(F0T, B, Wfp1, Yp, 80);
        reduce_kernel<<<((B * 80 / 4) + 255) / 256, 256, 0, stream>>>(h1T, Yp, B * 80, 9);
        // L2: 80->160, S=5 (KC=16), 2 col halves
        kan6_kernel<80, 16, 2><<<dim3(B / 128, 5, 2), 256, 0, stream>>>(h1T, B, Wfp2, Yp, 160);
        reduce_kernel<<<((B * 160 / 4) + 255) / 256, 256, 0, stream>>>(h2T, Yp, B * 160, 5);
        // L3: 160->80, S=10 (KC=16)
        kan6_kernel<80, 16, 1><<<dim3(B / 128, 10, 1), 256, 0, stream>>>(h2T, B, Wfp3, Yp, 80);
        reduce_kernel<<<((B * 80 / 4) + 255) / 256, 256, 0, stream>>>(h3T, Yp, B * 80, 10);
        // L4: 80->40, S=10 (KC=8)
        kan6_kernel<40, 8, 1><<<dim3(B / 128, 10, 1), 256, 0, stream>>>(h3T, B, Wfp4, Yp, 40);
        reduce_kernel<<<((B * 40 / 4) + 255) / 256, 256, 0, stream>>>(h4T, Yp, B * 40, 10);
    } else {
        kan6_kernel<80, 126, 1><<<dim3(B / 128, 3, 1), 256, 0, stream>>>(F0T, B, Wfp1, Yp, 80);
        reduce_kernel<<<((B * 80 / 4) + 255) / 256, 256, 0, stream>>>(h1T, Yp, B * 80, 3);
        kan6_kernel<80, 40, 2><<<dim3(B / 128, 2, 2), 256, 0, stream>>>(h1T, B, Wfp2, Yp, 160);
        reduce_kernel<<<((B * 160 / 4) + 255) / 256, 256, 0, stream>>>(h2T, Yp, B * 160, 2);
        kan6_kernel<80, 40, 1><<<dim3(B / 128, 4, 1), 256, 0, stream>>>(h2T, B, Wfp3, Yp, 80);
        reduce_kernel<<<((B * 80 / 4) + 255) / 256, 256, 0, stream>>>(h3T, Yp, B * 80, 4);
        kan6_kernel<40, 40, 1><<<dim3(B / 128, 2, 1), 256, 0, stream>>>(h3T, B, Wfp4, Yp, 40);
        reduce_kernel<<<((B * 40 / 4) + 255) / 256, 256, 0, stream>>>(h4T, Yp, B * 40, 2);
    }

    // ---- heads ----
    heads_kernel<<<(B * 3 + 255) / 256, 256, 0, stream>>>(h4T, W21, b21, hW3, hb3, out, B);

    (void)n_in; (void)out_size;
}